// Round 16
// baseline (251.726 us; speedup 1.0000x reference)
//
#include <hip/hip_runtime.h>
#include <math.h>

typedef unsigned short u16;
typedef __attribute__((ext_vector_type(8))) _Float16 half8;
typedef __attribute__((ext_vector_type(4))) float f32x4;
typedef __attribute__((ext_vector_type(4))) unsigned short us4;

// Inputs f32, output f32 (proven r4-15). All inter-kernel activations f16.
// r16: consolidation — state prefix folded into retention; transpose+ln1 merged.

static __device__ __forceinline__ u16 f2h(float f) {
    _Float16 h = (_Float16)f;
    return __builtin_bit_cast(u16, h);
}
static __device__ __forceinline__ float h2f(u16 u) {
    return (float)__builtin_bit_cast(_Float16, u);
}
static __device__ __forceinline__ void gl_lds16(const void* g, void* l) {
    __builtin_amdgcn_global_load_lds(
        (const __attribute__((address_space(1))) void*)g,
        (__attribute__((address_space(3))) void*)l, 16, 0, 0);
}

// ---------- prep: weight transpose (448 blocks) + embed-LN (2048 blocks) ----------
__global__ __launch_bounds__(256) void prep_kernel(
    const float* __restrict__ Wq, const float* __restrict__ Wk, const float* __restrict__ Wv,
    const float* __restrict__ Wg, const float* __restrict__ Wo, const float* __restrict__ W1,
    const float* __restrict__ W2, u16* __restrict__ WT,
    const int* __restrict__ ids, const float* __restrict__ emb, const float* __restrict__ pos,
    const float* __restrict__ gam, const float* __restrict__ bet, u16* __restrict__ x0h)
{
    __shared__ float tile[64][65];
    int bx = blockIdx.x, t = threadIdx.x;
    if (bx < 448) {
        const float* Ws[7] = {Wq, Wk, Wv, Wg, Wo, W1, W2};
        int w = bx >> 6, rem = bx & 63;
        int k0 = (rem >> 3) * 64, n0 = (rem & 7) * 64;
        const float* W = Ws[w];
        for (int c = t; c < 4096; c += 256) {
            int row = c >> 6, col = c & 63;
            tile[row][col] = W[(size_t)(k0 + row) * 512 + n0 + col];
        }
        __syncthreads();
        for (int c = t; c < 4096; c += 256) {
            int row = c >> 6, col = c & 63;
            WT[(size_t)w * 262144 + (size_t)(n0 + row) * 512 + k0 + col] = f2h(tile[col][row]);
        }
    } else {
        int wid = t >> 6, lane = t & 63;
        int row = (bx - 448) * 4 + wid;
        int col = lane * 8;
        int id = ids[2 * 8192 + row];
        const float* e = emb + (size_t)(2 * 1024 + id) * 512 + col;
        const float* p = pos + (size_t)(2 * 1024 + (row & 1023)) * 512 + col;
        float4 e0 = *(const float4*)e, e1 = *(const float4*)(e + 4);
        float4 p0 = *(const float4*)p, p1 = *(const float4*)(p + 4);
        float v[8] = {e0.x + p0.x, e0.y + p0.y, e0.z + p0.z, e0.w + p0.w,
                      e1.x + p1.x, e1.y + p1.y, e1.z + p1.z, e1.w + p1.w};
        float s1 = 0.f, s2 = 0.f;
#pragma unroll
        for (int j = 0; j < 8; ++j) { s1 += v[j]; s2 += v[j] * v[j]; }
#pragma unroll
        for (int o = 32; o >= 1; o >>= 1) {
            s1 += __shfl_xor(s1, o, 64);
            s2 += __shfl_xor(s2, o, 64);
        }
        float mu = s1 * (1.f / 512.f);
        float var = fmaxf(s2 * (1.f / 512.f) - mu * mu, 0.f);
        float rs = 1.f / sqrtf(var + 1e-5f);
        float4 g0 = *(const float4*)&gam[col], g1 = *(const float4*)&gam[col + 4];
        float4 b0 = *(const float4*)&bet[col], b1 = *(const float4*)&bet[col + 4];
        float gv[8] = {g0.x, g0.y, g0.z, g0.w, g1.x, g1.y, g1.z, g1.w};
        float bv[8] = {b0.x, b0.y, b0.z, b0.w, b1.x, b1.y, b1.z, b1.w};
        half8 hv;
#pragma unroll
        for (int j = 0; j < 8; ++j) hv[j] = (_Float16)((v[j] - mu) * rs * gv[j] + bv[j]);
        *(half8*)&x0h[(size_t)row * 512 + col] = hv;
    }
}

// ---------- LayerNorm, row-per-wave; optional fused FC partial ----------
__global__ __launch_bounds__(256) void ln_kernel(
    const u16* __restrict__ xin,
    const float* __restrict__ gam, const float* __restrict__ bet,
    u16* __restrict__ outh,
    const float* __restrict__ fcW, float* __restrict__ fcpart)
{
    int wid = threadIdx.x >> 6, lane = threadIdx.x & 63;
    int row = blockIdx.x * 4 + wid;
    int col = lane * 8;
    float v[8];
    half8 x = *(const half8*)&xin[(size_t)row * 512 + col];
#pragma unroll
    for (int j = 0; j < 8; ++j) v[j] = (float)x[j];
    float s1 = 0.f, s2 = 0.f;
#pragma unroll
    for (int j = 0; j < 8; ++j) { s1 += v[j]; s2 += v[j] * v[j]; }
#pragma unroll
    for (int o = 32; o >= 1; o >>= 1) {
        s1 += __shfl_xor(s1, o, 64);
        s2 += __shfl_xor(s2, o, 64);
    }
    float mu = s1 * (1.f / 512.f);
    float var = fmaxf(s2 * (1.f / 512.f) - mu * mu, 0.f);
    float rs = 1.f / sqrtf(var + 1e-5f);
    float4 g0 = *(const float4*)&gam[col], g1 = *(const float4*)&gam[col + 4];
    float4 b0 = *(const float4*)&bet[col], b1 = *(const float4*)&bet[col + 4];
    float gv[8] = {g0.x, g0.y, g0.z, g0.w, g1.x, g1.y, g1.z, g1.w};
    float bv[8] = {b0.x, b0.y, b0.z, b0.w, b1.x, b1.y, b1.z, b1.w};
    float y[8];
#pragma unroll
    for (int j = 0; j < 8; ++j) y[j] = (v[j] - mu) * rs * gv[j] + bv[j];
    if (outh) {
        half8 hv;
#pragma unroll
        for (int j = 0; j < 8; ++j) hv[j] = (_Float16)y[j];
        *(half8*)&outh[(size_t)row * 512 + col] = hv;
    }
    if (fcW) {
        int srow = row & 1023;
        const float* wp = &fcW[(size_t)srow * 512 + col];
        float4 w0 = *(const float4*)wp, w1 = *(const float4*)(wp + 4);
        float d = y[0] * w0.x + y[1] * w0.y + y[2] * w0.z + y[3] * w0.w +
                  y[4] * w1.x + y[5] * w1.y + y[6] * w1.z + y[7] * w1.w;
#pragma unroll
        for (int o = 32; o >= 1; o >>= 1) d += __shfl_xor(d, o, 64);
        if (lane == 0) fcpart[row] = d;
    }
}

// ---------- GEMM: outh = f16(A_f16 x B_f16^T [+ eps]); gl_lds staging, BK=64 ----------
__global__ __launch_bounds__(256) void gemm_f16(
    const u16* __restrict__ A2, const u16* __restrict__ Bg,
    u16* __restrict__ outh,
    const u16* __restrict__ res, const float* __restrict__ bias, int mode, int ostride)
{
    __shared__ u16 As[128 * 64];
    __shared__ u16 Bs[128 * 64];
    int t = threadIdx.x;
    int wid = t >> 6, lane = t & 63, quad = lane >> 4, l15 = lane & 15;
    int wm = wid >> 1, wn = wid & 1;
    int m0 = blockIdx.y * 128, n0 = blockIdx.x * 128;

    int srow = wid * 8 + (lane >> 3);
    int scol = (lane & 7) * 8;

    f32x4 acc[4][4];
#pragma unroll
    for (int a = 0; a < 4; ++a)
#pragma unroll
        for (int b = 0; b < 4; ++b) acc[a][b] = (f32x4){0.f, 0.f, 0.f, 0.f};

    for (int ki = 0; ki < 8; ++ki) {
        int k0 = ki * 64;
        __syncthreads();
#pragma unroll
        for (int i = 0; i < 4; ++i) {
            int r = i * 32 + srow;
            gl_lds16(&A2[(size_t)(m0 + r) * 512 + k0 + scol], &As[(i * 32 + wid * 8) * 64]);
            gl_lds16(&Bg[(size_t)(n0 + r) * 512 + k0 + scol], &Bs[(i * 32 + wid * 8) * 64]);
        }
        __syncthreads();
#pragma unroll
        for (int ks = 0; ks < 2; ++ks) {
            half8 af[4], bf[4];
#pragma unroll
            for (int tm = 0; tm < 4; ++tm)
                af[tm] = *(const half8*)&As[(wm * 64 + tm * 16 + l15) * 64 + ks * 32 + quad * 8];
#pragma unroll
            for (int tn = 0; tn < 4; ++tn)
                bf[tn] = *(const half8*)&Bs[(wn * 64 + tn * 16 + l15) * 64 + ks * 32 + quad * 8];
#pragma unroll
            for (int tm = 0; tm < 4; ++tm)
#pragma unroll
                for (int tn = 0; tn < 4; ++tn)
                    acc[tm][tn] = __builtin_amdgcn_mfma_f32_16x16x32_f16(af[tm], bf[tn], acc[tm][tn], 0, 0, 0);
        }
    }

#pragma unroll
    for (int tm = 0; tm < 4; ++tm) {
#pragma unroll
        for (int tn = 0; tn < 4; ++tn) {
            int n = n0 + wn * 64 + tn * 16 + l15;
            int mbase = m0 + wm * 64 + tm * 16 + quad * 4;
#pragma unroll
            for (int r = 0; r < 4; ++r) {
                int m = mbase + r;
                float v = acc[tm][tn][r];
                if (mode == 1) v += h2f(res[(size_t)m * 512 + n]);
                else if (mode == 2) v = fmaxf(v + bias[n], 0.f);
                else if (mode == 3) v += bias[n] + h2f(res[(size_t)m * 512 + n]);
                outh[(size_t)m * ostride + n] = f2h(v);
            }
        }
    }
}

// ---------- chunk T: per (b,h,c) parallel — T_c[d'][d] = sum_m v[m][d']*k[m][d]*g^(127-mloc) ----------
__global__ __launch_bounds__(256) void chunk_t(
    const u16* __restrict__ QKVGh, u16* __restrict__ Tst)
{
    __shared__ u16 kth[64 * 144];   // K^T (decay-scaled) [d][m], rotation-swizzled
    __shared__ u16 vth[64 * 144];   // V^T [d][m], rotation-swizzled
    int t = threadIdx.x;
    int wid = t >> 6, lane = t & 63, quad = lane >> 4, l15 = lane & 15;
    int bh = blockIdx.x >> 3, c = blockIdx.x & 7;
    int b = bh >> 3, h = bh & 7;
    float gamma = 1.f - exp2f(-(float)(5 + h));
    float l2g = log2f(gamma);

    for (int cc = t; cc < 2048; cc += 256) {
        int d = cc & 63, mseg = cc >> 6;
        size_t gbase = (size_t)(b * 1024 + c * 128 + mseg * 4) * 2048 + h * 64 + d;
        us4 k4, v4;
#pragma unroll
        for (int i = 0; i < 4; ++i) {
            float kv = h2f(QKVGh[gbase + 512 + (size_t)i * 2048]);
            k4[i] = f2h(kv * exp2f((float)(127 - (mseg * 4 + i)) * l2g));
            v4[i] = QKVGh[gbase + 1024 + (size_t)i * 2048];
        }
        int base = d * 144 + (((mseg >> 1) + d) & 15) * 8 + (mseg & 1) * 4;
        *(us4*)&kth[base] = k4;
        *(us4*)&vth[base] = v4;
    }
    __syncthreads();
    f32x4 T[4];
#pragma unroll
    for (int dt = 0; dt < 4; ++dt) T[dt] = (f32x4){0.f, 0.f, 0.f, 0.f};
    int ra = wid * 16 + l15;   // A rows: d'
#pragma unroll
    for (int ks = 0; ks < 4; ++ks) {
        half8 av = *(const half8*)&vth[ra * 144 + ((ks * 4 + quad + ra) & 15) * 8];
#pragma unroll
        for (int dt = 0; dt < 4; ++dt) {
            int rb = dt * 16 + l15;
            half8 bk = *(const half8*)&kth[rb * 144 + ((ks * 4 + quad + rb) & 15) * 8];
            T[dt] = __builtin_amdgcn_mfma_f32_16x16x32_f16(av, bk, T[dt], 0, 0, 0);
        }
    }
#pragma unroll
    for (int dt = 0; dt < 4; ++dt)
#pragma unroll
        for (int r = 0; r < 4; ++r) {
            int i = wid * 16 + quad * 4 + r;   // d' (D row)
            int j = dt * 16 + l15;             // d  (D col)
            Tst[(((size_t)bh * 8 + c) * 64 + i) * 64 + j] = f2h(T[dt][r]);
        }
}

// ---------- retention: inline state prefix from Tst + single-chunk intra ----------
__global__ __launch_bounds__(256) void retention_f16(
    const u16* __restrict__ QKVGh, const u16* __restrict__ Tst, u16* __restrict__ Zh)
{
    __shared__ u16 kh[128 * 64];       // K tile [m][d], unpadded (gl_lds layout)
    __shared__ u16 vth[64 * 144];      // V^T [d][m=128], rotation-swizzled
    __shared__ u16 ph[4][16 * 132];    // per-wave per-group P

    int t = threadIdx.x;
    int wid = t >> 6, lane = t & 63, quad = lane >> 4, l15 = lane & 15;
    int bh = blockIdx.x >> 3, qt = blockIdx.x & 7;
    int b = bh >> 3, h = bh & 7;
    int n0 = qt * 128;

    float gamma = 1.f - exp2f(-(float)(5 + h));
    float l2g = log2f(gamma);

    // K tile via global_load_lds (contiguous lane*16B, m97 pattern)
    {
        int srow = wid * 8 + (lane >> 3);
        int scol = (lane & 7) * 8;
#pragma unroll
        for (int i = 0; i < 4; ++i) {
            int r = i * 32 + srow;
            gl_lds16(&QKVGh[(size_t)(b * 1024 + n0 + r) * 2048 + 512 + h * 64 + scol],
                     &kh[(i * 32 + wid * 8) * 64]);
        }
    }
    // V^T tile: manual transpose + rotation swizzle
    for (int c = t; c < 2048; c += 256) {
        int d = c & 63, mseg = c >> 6;
        size_t gbase = (size_t)(b * 1024 + n0 + mseg * 4) * 2048 + 1024 + h * 64 + d;
        us4 v4 = {QKVGh[gbase], QKVGh[gbase + 2048],
                  QKVGh[gbase + 4096], QKVGh[gbase + 6144]};
        int base = d * 144 + (((mseg >> 1) + d) & 15) * 8 + (mseg & 1) * 4;
        *(us4*)&vth[base] = v4;
    }

    // Q frags + inter-scaled copy
    half8 aH[2][2], aHs[2][2];
#pragma unroll
    for (int g = 0; g < 2; ++g) {
        int rowloc = wid * 32 + g * 16 + l15;
        int qrow = b * 1024 + n0 + rowloc;
        const u16* qp = QKVGh + (size_t)qrow * 2048 + h * 64;
        float qs = exp2f((float)(rowloc + 1) * l2g - 3.f);
#pragma unroll
        for (int ks = 0; ks < 2; ++ks) {
            aH[g][ks] = *(const half8*)&qp[ks * 32 + quad * 8];
#pragma unroll
            for (int j = 0; j < 8; ++j)
                aHs[g][ks][j] = (_Float16)((float)aH[g][ks][j] * qs);
        }
    }

    // inline state prefix: S = sum_{c<qt} g^(128(qt-1-c)) T_c  (B-frag layout, f32 accum)
    half8 sf[2][4];
    if (qt > 0) {
        float sa[2][4][8];
#pragma unroll
        for (int ks = 0; ks < 2; ++ks)
#pragma unroll
            for (int dt = 0; dt < 4; ++dt)
#pragma unroll
                for (int j = 0; j < 8; ++j) sa[ks][dt][j] = 0.f;
        for (int c = 0; c < qt; ++c) {
            float sc = exp2f((float)(128 * (qt - 1 - c)) * l2g);
            const u16* tp = &Tst[((size_t)bh * 8 + c) * 4096];
#pragma unroll
            for (int ks = 0; ks < 2; ++ks)
#pragma unroll
                for (int dt = 0; dt < 4; ++dt) {
                    half8 tv = *(const half8*)&tp[(dt * 16 + l15) * 64 + ks * 32 + quad * 8];
#pragma unroll
                    for (int j = 0; j < 8; ++j) sa[ks][dt][j] += sc * (float)tv[j];
                }
        }
#pragma unroll
        for (int ks = 0; ks < 2; ++ks)
#pragma unroll
            for (int dt = 0; dt < 4; ++dt)
#pragma unroll
                for (int j = 0; j < 8; ++j) sf[ks][dt][j] = (_Float16)sa[ks][dt][j];
    }
    __syncthreads();

    f32x4 yacc[2][4];
#pragma unroll
    for (int g = 0; g < 2; ++g)
#pragma unroll
        for (int dt = 0; dt < 4; ++dt) yacc[g][dt] = (f32x4){0.f, 0.f, 0.f, 0.f};

    // inter-chunk: y += qs . S
    if (qt > 0) {
#pragma unroll
        for (int ks = 0; ks < 2; ++ks)
#pragma unroll
            for (int g = 0; g < 2; ++g)
#pragma unroll
                for (int dt = 0; dt < 4; ++dt)
                    yacc[g][dt] = __builtin_amdgcn_mfma_f32_16x16x32_f16(aHs[g][ks], sf[ks][dt], yacc[g][dt], 0, 0, 0);
    }

    // intra-chunk: QK^T -> decay -> P -> PV
#pragma unroll
    for (int g = 0; g < 2; ++g) {
        f32x4 sacc[8];
#pragma unroll
        for (int tn = 0; tn < 8; ++tn) sacc[tn] = (f32x4){0.f, 0.f, 0.f, 0.f};
#pragma unroll
        for (int tn = 0; tn < 8; ++tn)
#pragma unroll
            for (int ks = 0; ks < 2; ++ks) {
                half8 bH = *(const half8*)&kh[(tn * 16 + l15) * 64 + ks * 32 + quad * 8];
                sacc[tn] = __builtin_amdgcn_mfma_f32_16x16x32_f16(aH[g][ks], bH, sacc[tn], 0, 0, 0);
            }
#pragma unroll
        for (int tn = 0; tn < 8; ++tn) {
            int mloc = tn * 16 + l15;
#pragma unroll
            for (int r = 0; r < 4; ++r) {
                int nloc = wid * 32 + g * 16 + quad * 4 + r;
                int diff = nloc - mloc;
                float p = (diff >= 0) ? sacc[tn][r] * exp2f((float)diff * l2g - 3.0f) : 0.f;
                ph[wid][(quad * 4 + r) * 132 + tn * 16 + l15] = f2h(p);
            }
        }
        half8 pH[4];
#pragma unroll
        for (int ks = 0; ks < 4; ++ks)
            pH[ks] = *(const half8*)&ph[wid][l15 * 132 + ks * 32 + quad * 8];
#pragma unroll
        for (int dt = 0; dt < 4; ++dt) {
            int d = dt * 16 + l15;
#pragma unroll
            for (int ks = 0; ks < 4; ++ks) {
                half8 vv = *(const half8*)&vth[d * 144 + ((ks * 4 + quad + d) & 15) * 8];
                yacc[g][dt] = __builtin_amdgcn_mfma_f32_16x16x32_f16(pH[ks], vv, yacc[g][dt], 0, 0, 0);
            }
        }
    }

    // per-q-row groupnorm + swish gate + f16 store
#pragma unroll
    for (int g = 0; g < 2; ++g) {
#pragma unroll
        for (int r = 0; r < 4; ++r) {
            float s1 = yacc[g][0][r] + yacc[g][1][r] + yacc[g][2][r] + yacc[g][3][r];
            float s2 = yacc[g][0][r] * yacc[g][0][r] + yacc[g][1][r] * yacc[g][1][r] +
                       yacc[g][2][r] * yacc[g][2][r] + yacc[g][3][r] * yacc[g][3][r];
#pragma unroll
            for (int o = 1; o <= 8; o <<= 1) {
                s1 += __shfl_xor(s1, o, 64);
                s2 += __shfl_xor(s2, o, 64);
            }
            float mu = s1 * (1.f / 64.f);
            float var = fmaxf(s2 * (1.f / 64.f) - mu * mu, 0.f);
            float rs = 1.f / sqrtf(var + 1e-5f);
            int nglob = n0 + wid * 32 + g * 16 + quad * 4 + r;
            size_t grow = (size_t)(b * 1024 + nglob);
#pragma unroll
            for (int dt = 0; dt < 4; ++dt) {
                int d = dt * 16 + l15;
                float yv = (yacc[g][dt][r] - mu) * rs;
                float gt = h2f(QKVGh[grow * 2048 + 1536 + h * 64 + d]);
                float sw = gt / (1.f + expf(-gt));
                Zh[grow * 512 + h * 64 + d] = f2h(yv * sw);
            }
        }
    }
}

// ---------- final reduce ----------
__global__ __launch_bounds__(256) void fc_final(const float* __restrict__ fcpart,
                                                const float* __restrict__ fcb,
                                                float* __restrict__ out)
{
    __shared__ float red[4];
    int b = blockIdx.x, t = threadIdx.x;
    float4 v = *(const float4*)&fcpart[(size_t)b * 1024 + t * 4];
    float s = v.x + v.y + v.z + v.w;
    int wid = t >> 6, lane = t & 63;
#pragma unroll
    for (int o = 32; o >= 1; o >>= 1) s += __shfl_xor(s, o, 64);
    if (lane == 0) red[wid] = s;
    __syncthreads();
    if (t == 0) {
        float l = red[0] + red[1] + red[2] + red[3] + fcb[0];
        out[b] = 1.f / (1.f + expf(-l));
    }
}

extern "C" void kernel_launch(void* const* d_in, const int* in_sizes, int n_in,
                              void* d_out, int out_size, void* d_ws, size_t ws_size,
                              hipStream_t stream)
{
    const int* ids = (const int*)d_in[0];
    const float* emb = (const float*)d_in[1];
    const float* pos = (const float*)d_in[2];
    const float* ln_g = (const float*)d_in[3];
    const float* ln_b = (const float*)d_in[4];
    const float* Wq = (const float*)d_in[5];
    const float* Wk = (const float*)d_in[6];
    const float* Wv = (const float*)d_in[7];
    const float* Wg = (const float*)d_in[8];
    const float* Wo = (const float*)d_in[9];
    const float* W1 = (const float*)d_in[10];
    const float* b1 = (const float*)d_in[11];
    const float* W2 = (const float*)d_in[12];
    const float* b2 = (const float*)d_in[13];
    const float* fcW = (const float*)d_in[14];
    const float* fcb = (const float*)d_in[15];
    float* out = (float*)d_out;

    char* ws = (char*)d_ws;
    u16* WT     = (u16*)(ws);                  //  3,670,016
    u16* x0h    = (u16*)(ws + 3670016);        //  8,388,608  LN(emb) f16 (A + residual)
    u16* Zh     = (u16*)(ws + 12058624);       //  8,388,608  retention out f16
    u16* QKVGh  = (u16*)(ws + 20447232);       // 33,554,432  [8192][2048] f16
    float* fcpart = (float*)(ws + 54001664);   // 32,768
    u16* Tst    = (u16*)(ws + 54034432);       //  4,194,304  per-chunk T [64bh][8][64][64]
    u16* X1h = QKVGh;                           // Wo out (residual for W2)
    u16* Th  = (u16*)((char*)QKVGh + 8388608);  // ln2 out
    u16* Hh  = (u16*)((char*)QKVGh + 16777216); // W1 out
    u16* X2h = Zh;                              // Zh dead after Wo-GEMM

    // only vocab iteration i=2 is live (x overwritten each pass)
    prep_kernel<<<2496, 256, 0, stream>>>(Wq, Wk, Wv, Wg, Wo, W1, W2, WT,
                                          ids, emb, pos, ln_g, ln_b, x0h);
    gemm_f16<<<dim3(16, 64), 256, 0, stream>>>(x0h, WT, QKVGh, nullptr, nullptr, 0, 2048);
    chunk_t<<<512, 256, 0, stream>>>(QKVGh, Tst);
    retention_f16<<<512, 256, 0, stream>>>(QKVGh, Tst, Zh);
    gemm_f16<<<dim3(4, 64), 256, 0, stream>>>(Zh, WT + 4 * 262144, X1h, x0h, nullptr, 1, 512);
    ln_kernel<<<2048, 256, 0, stream>>>(X1h, ln_g, ln_b, Th, nullptr, nullptr);
    gemm_f16<<<dim3(4, 64), 256, 0, stream>>>(Th, WT + 5 * 262144, Hh, nullptr, b1, 2, 512);
    gemm_f16<<<dim3(4, 64), 256, 0, stream>>>(Hh, WT + 6 * 262144, X2h, X1h, b2, 3, 512);
    ln_kernel<<<2048, 256, 0, stream>>>(X2h, ln_g, ln_b, nullptr, fcW, fcpart);
    fc_final<<<8, 256, 0, stream>>>(fcpart, fcb, out);
}

// Round 17
// 230.685 us; speedup vs baseline: 1.0912x; 1.0912x over previous
//
#include <hip/hip_runtime.h>
#include <math.h>

typedef unsigned short u16;
typedef __attribute__((ext_vector_type(8))) _Float16 half8;
typedef __attribute__((ext_vector_type(4))) float f32x4;
typedef __attribute__((ext_vector_type(4))) unsigned short us4;

// Inputs f32, output f32 (proven r4-16). All inter-kernel activations f16.
// r17: N=512 GEMMs -> 128x64 tiles (512 blocks, 2/CU) to fix 1-block/CU latency exposure.

static __device__ __forceinline__ u16 f2h(float f) {
    _Float16 h = (_Float16)f;
    return __builtin_bit_cast(u16, h);
}
static __device__ __forceinline__ float h2f(u16 u) {
    return (float)__builtin_bit_cast(_Float16, u);
}
static __device__ __forceinline__ void gl_lds16(const void* g, void* l) {
    __builtin_amdgcn_global_load_lds(
        (const __attribute__((address_space(1))) void*)g,
        (__attribute__((address_space(3))) void*)l, 16, 0, 0);
}

// ---------- prep: weight transpose (448 blocks) + embed-LN (2048 blocks) ----------
__global__ __launch_bounds__(256) void prep_kernel(
    const float* __restrict__ Wq, const float* __restrict__ Wk, const float* __restrict__ Wv,
    const float* __restrict__ Wg, const float* __restrict__ Wo, const float* __restrict__ W1,
    const float* __restrict__ W2, u16* __restrict__ WT,
    const int* __restrict__ ids, const float* __restrict__ emb, const float* __restrict__ pos,
    const float* __restrict__ gam, const float* __restrict__ bet, u16* __restrict__ x0h)
{
    __shared__ float tile[64][65];
    int bx = blockIdx.x, t = threadIdx.x;
    if (bx < 448) {
        const float* Ws[7] = {Wq, Wk, Wv, Wg, Wo, W1, W2};
        int w = bx >> 6, rem = bx & 63;
        int k0 = (rem >> 3) * 64, n0 = (rem & 7) * 64;
        const float* W = Ws[w];
        for (int c = t; c < 4096; c += 256) {
            int row = c >> 6, col = c & 63;
            tile[row][col] = W[(size_t)(k0 + row) * 512 + n0 + col];
        }
        __syncthreads();
        for (int c = t; c < 4096; c += 256) {
            int row = c >> 6, col = c & 63;
            WT[(size_t)w * 262144 + (size_t)(n0 + row) * 512 + k0 + col] = f2h(tile[col][row]);
        }
    } else {
        int wid = t >> 6, lane = t & 63;
        int row = (bx - 448) * 4 + wid;
        int col = lane * 8;
        int id = ids[2 * 8192 + row];
        const float* e = emb + (size_t)(2 * 1024 + id) * 512 + col;
        const float* p = pos + (size_t)(2 * 1024 + (row & 1023)) * 512 + col;
        float4 e0 = *(const float4*)e, e1 = *(const float4*)(e + 4);
        float4 p0 = *(const float4*)p, p1 = *(const float4*)(p + 4);
        float v[8] = {e0.x + p0.x, e0.y + p0.y, e0.z + p0.z, e0.w + p0.w,
                      e1.x + p1.x, e1.y + p1.y, e1.z + p1.z, e1.w + p1.w};
        float s1 = 0.f, s2 = 0.f;
#pragma unroll
        for (int j = 0; j < 8; ++j) { s1 += v[j]; s2 += v[j] * v[j]; }
#pragma unroll
        for (int o = 32; o >= 1; o >>= 1) {
            s1 += __shfl_xor(s1, o, 64);
            s2 += __shfl_xor(s2, o, 64);
        }
        float mu = s1 * (1.f / 512.f);
        float var = fmaxf(s2 * (1.f / 512.f) - mu * mu, 0.f);
        float rs = 1.f / sqrtf(var + 1e-5f);
        float4 g0 = *(const float4*)&gam[col], g1 = *(const float4*)&gam[col + 4];
        float4 b0 = *(const float4*)&bet[col], b1 = *(const float4*)&bet[col + 4];
        float gv[8] = {g0.x, g0.y, g0.z, g0.w, g1.x, g1.y, g1.z, g1.w};
        float bv[8] = {b0.x, b0.y, b0.z, b0.w, b1.x, b1.y, b1.z, b1.w};
        half8 hv;
#pragma unroll
        for (int j = 0; j < 8; ++j) hv[j] = (_Float16)((v[j] - mu) * rs * gv[j] + bv[j]);
        *(half8*)&x0h[(size_t)row * 512 + col] = hv;
    }
}

// ---------- LayerNorm, row-per-wave; optional fused FC partial ----------
__global__ __launch_bounds__(256) void ln_kernel(
    const u16* __restrict__ xin,
    const float* __restrict__ gam, const float* __restrict__ bet,
    u16* __restrict__ outh,
    const float* __restrict__ fcW, float* __restrict__ fcpart)
{
    int wid = threadIdx.x >> 6, lane = threadIdx.x & 63;
    int row = blockIdx.x * 4 + wid;
    int col = lane * 8;
    float v[8];
    half8 x = *(const half8*)&xin[(size_t)row * 512 + col];
#pragma unroll
    for (int j = 0; j < 8; ++j) v[j] = (float)x[j];
    float s1 = 0.f, s2 = 0.f;
#pragma unroll
    for (int j = 0; j < 8; ++j) { s1 += v[j]; s2 += v[j] * v[j]; }
#pragma unroll
    for (int o = 32; o >= 1; o >>= 1) {
        s1 += __shfl_xor(s1, o, 64);
        s2 += __shfl_xor(s2, o, 64);
    }
    float mu = s1 * (1.f / 512.f);
    float var = fmaxf(s2 * (1.f / 512.f) - mu * mu, 0.f);
    float rs = 1.f / sqrtf(var + 1e-5f);
    float4 g0 = *(const float4*)&gam[col], g1 = *(const float4*)&gam[col + 4];
    float4 b0 = *(const float4*)&bet[col], b1 = *(const float4*)&bet[col + 4];
    float gv[8] = {g0.x, g0.y, g0.z, g0.w, g1.x, g1.y, g1.z, g1.w};
    float bv[8] = {b0.x, b0.y, b0.z, b0.w, b1.x, b1.y, b1.z, b1.w};
    float y[8];
#pragma unroll
    for (int j = 0; j < 8; ++j) y[j] = (v[j] - mu) * rs * gv[j] + bv[j];
    if (outh) {
        half8 hv;
#pragma unroll
        for (int j = 0; j < 8; ++j) hv[j] = (_Float16)y[j];
        *(half8*)&outh[(size_t)row * 512 + col] = hv;
    }
    if (fcW) {
        int srow = row & 1023;
        const float* wp = &fcW[(size_t)srow * 512 + col];
        float4 w0 = *(const float4*)wp, w1 = *(const float4*)(wp + 4);
        float d = y[0] * w0.x + y[1] * w0.y + y[2] * w0.z + y[3] * w0.w +
                  y[4] * w1.x + y[5] * w1.y + y[6] * w1.z + y[7] * w1.w;
#pragma unroll
        for (int o = 32; o >= 1; o >>= 1) d += __shfl_xor(d, o, 64);
        if (lane == 0) fcpart[row] = d;
    }
}

// ---------- GEMM 128x128 tile (QKVG, N=2048): gl_lds staging, BK=64 ----------
__global__ __launch_bounds__(256) void gemm_f16(
    const u16* __restrict__ A2, const u16* __restrict__ Bg,
    u16* __restrict__ outh, int ostride)
{
    __shared__ u16 As[128 * 64];
    __shared__ u16 Bs[128 * 64];
    int t = threadIdx.x;
    int wid = t >> 6, lane = t & 63, quad = lane >> 4, l15 = lane & 15;
    int wm = wid >> 1, wn = wid & 1;
    int m0 = blockIdx.y * 128, n0 = blockIdx.x * 128;

    int srow = wid * 8 + (lane >> 3);
    int scol = (lane & 7) * 8;

    f32x4 acc[4][4];
#pragma unroll
    for (int a = 0; a < 4; ++a)
#pragma unroll
        for (int b = 0; b < 4; ++b) acc[a][b] = (f32x4){0.f, 0.f, 0.f, 0.f};

    for (int ki = 0; ki < 8; ++ki) {
        int k0 = ki * 64;
        __syncthreads();
#pragma unroll
        for (int i = 0; i < 4; ++i) {
            int r = i * 32 + srow;
            gl_lds16(&A2[(size_t)(m0 + r) * 512 + k0 + scol], &As[(i * 32 + wid * 8) * 64]);
            gl_lds16(&Bg[(size_t)(n0 + r) * 512 + k0 + scol], &Bs[(i * 32 + wid * 8) * 64]);
        }
        __syncthreads();
#pragma unroll
        for (int ks = 0; ks < 2; ++ks) {
            half8 af[4], bf[4];
#pragma unroll
            for (int tm = 0; tm < 4; ++tm)
                af[tm] = *(const half8*)&As[(wm * 64 + tm * 16 + l15) * 64 + ks * 32 + quad * 8];
#pragma unroll
            for (int tn = 0; tn < 4; ++tn)
                bf[tn] = *(const half8*)&Bs[(wn * 64 + tn * 16 + l15) * 64 + ks * 32 + quad * 8];
#pragma unroll
            for (int tm = 0; tm < 4; ++tm)
#pragma unroll
                for (int tn = 0; tn < 4; ++tn)
                    acc[tm][tn] = __builtin_amdgcn_mfma_f32_16x16x32_f16(af[tm], bf[tn], acc[tm][tn], 0, 0, 0);
        }
    }

#pragma unroll
    for (int tm = 0; tm < 4; ++tm) {
#pragma unroll
        for (int tn = 0; tn < 4; ++tn) {
            int n = n0 + wn * 64 + tn * 16 + l15;
            int mbase = m0 + wm * 64 + tm * 16 + quad * 4;
#pragma unroll
            for (int r = 0; r < 4; ++r)
                outh[(size_t)(mbase + r) * ostride + n] = f2h(acc[tm][tn][r]);
        }
    }
}

// ---------- GEMM 128x64 tile (N=512 layers): 512 blocks -> 2/CU ----------
// mode 1: C+res16 ; 2: relu(C+bias) ; 3: C+bias+res16
__global__ __launch_bounds__(256) void gemm_f16_n64(
    const u16* __restrict__ A2, const u16* __restrict__ Bg,
    u16* __restrict__ outh,
    const u16* __restrict__ res, const float* __restrict__ bias, int mode)
{
    __shared__ u16 As[128 * 64];   // 16 KB
    __shared__ u16 Bs[64 * 64];    //  8 KB
    int t = threadIdx.x;
    int wid = t >> 6, lane = t & 63, quad = lane >> 4, l15 = lane & 15;
    int m0 = blockIdx.y * 128, n0 = blockIdx.x * 64;

    int srow = wid * 8 + (lane >> 3);
    int scol = (lane & 7) * 8;

    f32x4 acc[2][4];
#pragma unroll
    for (int a = 0; a < 2; ++a)
#pragma unroll
        for (int b = 0; b < 4; ++b) acc[a][b] = (f32x4){0.f, 0.f, 0.f, 0.f};

    for (int ki = 0; ki < 8; ++ki) {
        int k0 = ki * 64;
        __syncthreads();
#pragma unroll
        for (int i = 0; i < 4; ++i) {
            int r = i * 32 + srow;
            gl_lds16(&A2[(size_t)(m0 + r) * 512 + k0 + scol], &As[(i * 32 + wid * 8) * 64]);
        }
#pragma unroll
        for (int i = 0; i < 2; ++i) {
            int r = i * 32 + srow;
            gl_lds16(&Bg[(size_t)(n0 + r) * 512 + k0 + scol], &Bs[(i * 32 + wid * 8) * 64]);
        }
        __syncthreads();
#pragma unroll
        for (int ks = 0; ks < 2; ++ks) {
            half8 af[2], bf[4];
#pragma unroll
            for (int tm = 0; tm < 2; ++tm)
                af[tm] = *(const half8*)&As[(wid * 32 + tm * 16 + l15) * 64 + ks * 32 + quad * 8];
#pragma unroll
            for (int tn = 0; tn < 4; ++tn)
                bf[tn] = *(const half8*)&Bs[(tn * 16 + l15) * 64 + ks * 32 + quad * 8];
#pragma unroll
            for (int tm = 0; tm < 2; ++tm)
#pragma unroll
                for (int tn = 0; tn < 4; ++tn)
                    acc[tm][tn] = __builtin_amdgcn_mfma_f32_16x16x32_f16(af[tm], bf[tn], acc[tm][tn], 0, 0, 0);
        }
    }

#pragma unroll
    for (int tm = 0; tm < 2; ++tm) {
#pragma unroll
        for (int tn = 0; tn < 4; ++tn) {
            int n = n0 + tn * 16 + l15;
            int mbase = m0 + wid * 32 + tm * 16 + quad * 4;
#pragma unroll
            for (int r = 0; r < 4; ++r) {
                int m = mbase + r;
                float v = acc[tm][tn][r];
                if (mode == 1) v += h2f(res[(size_t)m * 512 + n]);
                else if (mode == 2) v = fmaxf(v + bias[n], 0.f);
                else if (mode == 3) v += bias[n] + h2f(res[(size_t)m * 512 + n]);
                outh[(size_t)m * 512 + n] = f2h(v);
            }
        }
    }
}

// ---------- chunk T: per (b,h,c) — T_c[d'][d] = sum_m v[m][d']*k[m][d]*g^(127-mloc) ----------
__global__ __launch_bounds__(256) void chunk_t(
    const u16* __restrict__ QKVGh, u16* __restrict__ Tst)
{
    __shared__ u16 kth[64 * 144];
    __shared__ u16 vth[64 * 144];
    int t = threadIdx.x;
    int wid = t >> 6, lane = t & 63, quad = lane >> 4, l15 = lane & 15;
    int bh = blockIdx.x >> 3, c = blockIdx.x & 7;
    int b = bh >> 3, h = bh & 7;
    float gamma = 1.f - exp2f(-(float)(5 + h));
    float l2g = log2f(gamma);

    for (int cc = t; cc < 2048; cc += 256) {
        int d = cc & 63, mseg = cc >> 6;
        size_t gbase = (size_t)(b * 1024 + c * 128 + mseg * 4) * 2048 + h * 64 + d;
        us4 k4, v4;
#pragma unroll
        for (int i = 0; i < 4; ++i) {
            float kv = h2f(QKVGh[gbase + 512 + (size_t)i * 2048]);
            k4[i] = f2h(kv * exp2f((float)(127 - (mseg * 4 + i)) * l2g));
            v4[i] = QKVGh[gbase + 1024 + (size_t)i * 2048];
        }
        int base = d * 144 + (((mseg >> 1) + d) & 15) * 8 + (mseg & 1) * 4;
        *(us4*)&kth[base] = k4;
        *(us4*)&vth[base] = v4;
    }
    __syncthreads();
    f32x4 T[4];
#pragma unroll
    for (int dt = 0; dt < 4; ++dt) T[dt] = (f32x4){0.f, 0.f, 0.f, 0.f};
    int ra = wid * 16 + l15;
#pragma unroll
    for (int ks = 0; ks < 4; ++ks) {
        half8 av = *(const half8*)&vth[ra * 144 + ((ks * 4 + quad + ra) & 15) * 8];
#pragma unroll
        for (int dt = 0; dt < 4; ++dt) {
            int rb = dt * 16 + l15;
            half8 bk = *(const half8*)&kth[rb * 144 + ((ks * 4 + quad + rb) & 15) * 8];
            T[dt] = __builtin_amdgcn_mfma_f32_16x16x32_f16(av, bk, T[dt], 0, 0, 0);
        }
    }
#pragma unroll
    for (int dt = 0; dt < 4; ++dt)
#pragma unroll
        for (int r = 0; r < 4; ++r) {
            int i = wid * 16 + quad * 4 + r;
            int j = dt * 16 + l15;
            Tst[(((size_t)bh * 8 + c) * 64 + i) * 64 + j] = f2h(T[dt][r]);
        }
}

// ---------- retention: inline state prefix from Tst + single-chunk intra ----------
__global__ __launch_bounds__(256) void retention_f16(
    const u16* __restrict__ QKVGh, const u16* __restrict__ Tst, u16* __restrict__ Zh)
{
    __shared__ u16 kh[128 * 64];
    __shared__ u16 vth[64 * 144];
    __shared__ u16 ph[4][16 * 132];

    int t = threadIdx.x;
    int wid = t >> 6, lane = t & 63, quad = lane >> 4, l15 = lane & 15;
    int bh = blockIdx.x >> 3, qt = blockIdx.x & 7;
    int b = bh >> 3, h = bh & 7;
    int n0 = qt * 128;

    float gamma = 1.f - exp2f(-(float)(5 + h));
    float l2g = log2f(gamma);

    {
        int srow = wid * 8 + (lane >> 3);
        int scol = (lane & 7) * 8;
#pragma unroll
        for (int i = 0; i < 4; ++i) {
            int r = i * 32 + srow;
            gl_lds16(&QKVGh[(size_t)(b * 1024 + n0 + r) * 2048 + 512 + h * 64 + scol],
                     &kh[(i * 32 + wid * 8) * 64]);
        }
    }
    for (int c = t; c < 2048; c += 256) {
        int d = c & 63, mseg = c >> 6;
        size_t gbase = (size_t)(b * 1024 + n0 + mseg * 4) * 2048 + 1024 + h * 64 + d;
        us4 v4 = {QKVGh[gbase], QKVGh[gbase + 2048],
                  QKVGh[gbase + 4096], QKVGh[gbase + 6144]};
        int base = d * 144 + (((mseg >> 1) + d) & 15) * 8 + (mseg & 1) * 4;
        *(us4*)&vth[base] = v4;
    }

    half8 aH[2][2], aHs[2][2];
#pragma unroll
    for (int g = 0; g < 2; ++g) {
        int rowloc = wid * 32 + g * 16 + l15;
        int qrow = b * 1024 + n0 + rowloc;
        const u16* qp = QKVGh + (size_t)qrow * 2048 + h * 64;
        float qs = exp2f((float)(rowloc + 1) * l2g - 3.f);
#pragma unroll
        for (int ks = 0; ks < 2; ++ks) {
            aH[g][ks] = *(const half8*)&qp[ks * 32 + quad * 8];
#pragma unroll
            for (int j = 0; j < 8; ++j)
                aHs[g][ks][j] = (_Float16)((float)aH[g][ks][j] * qs);
        }
    }

    half8 sf[2][4];
    if (qt > 0) {
        float sa[2][4][8];
#pragma unroll
        for (int ks = 0; ks < 2; ++ks)
#pragma unroll
            for (int dt = 0; dt < 4; ++dt)
#pragma unroll
                for (int j = 0; j < 8; ++j) sa[ks][dt][j] = 0.f;
        for (int c = 0; c < qt; ++c) {
            float sc = exp2f((float)(128 * (qt - 1 - c)) * l2g);
            const u16* tp = &Tst[((size_t)bh * 8 + c) * 4096];
#pragma unroll
            for (int ks = 0; ks < 2; ++ks)
#pragma unroll
                for (int dt = 0; dt < 4; ++dt) {
                    half8 tv = *(const half8*)&tp[(dt * 16 + l15) * 64 + ks * 32 + quad * 8];
#pragma unroll
                    for (int j = 0; j < 8; ++j) sa[ks][dt][j] += sc * (float)tv[j];
                }
        }
#pragma unroll
        for (int ks = 0; ks < 2; ++ks)
#pragma unroll
            for (int dt = 0; dt < 4; ++dt)
#pragma unroll
                for (int j = 0; j < 8; ++j) sf[ks][dt][j] = (_Float16)sa[ks][dt][j];
    }
    __syncthreads();

    f32x4 yacc[2][4];
#pragma unroll
    for (int g = 0; g < 2; ++g)
#pragma unroll
        for (int dt = 0; dt < 4; ++dt) yacc[g][dt] = (f32x4){0.f, 0.f, 0.f, 0.f};

    if (qt > 0) {
#pragma unroll
        for (int ks = 0; ks < 2; ++ks)
#pragma unroll
            for (int g = 0; g < 2; ++g)
#pragma unroll
                for (int dt = 0; dt < 4; ++dt)
                    yacc[g][dt] = __builtin_amdgcn_mfma_f32_16x16x32_f16(aHs[g][ks], sf[ks][dt], yacc[g][dt], 0, 0, 0);
    }

#pragma unroll
    for (int g = 0; g < 2; ++g) {
        f32x4 sacc[8];
#pragma unroll
        for (int tn = 0; tn < 8; ++tn) sacc[tn] = (f32x4){0.f, 0.f, 0.f, 0.f};
#pragma unroll
        for (int tn = 0; tn < 8; ++tn)
#pragma unroll
            for (int ks = 0; ks < 2; ++ks) {
                half8 bH = *(const half8*)&kh[(tn * 16 + l15) * 64 + ks * 32 + quad * 8];
                sacc[tn] = __builtin_amdgcn_mfma_f32_16x16x32_f16(aH[g][ks], bH, sacc[tn], 0, 0, 0);
            }
#pragma unroll
        for (int tn = 0; tn < 8; ++tn) {
            int mloc = tn * 16 + l15;
#pragma unroll
            for (int r = 0; r < 4; ++r) {
                int nloc = wid * 32 + g * 16 + quad * 4 + r;
                int diff = nloc - mloc;
                float p = (diff >= 0) ? sacc[tn][r] * exp2f((float)diff * l2g - 3.0f) : 0.f;
                ph[wid][(quad * 4 + r) * 132 + tn * 16 + l15] = f2h(p);
            }
        }
        half8 pH[4];
#pragma unroll
        for (int ks = 0; ks < 4; ++ks)
            pH[ks] = *(const half8*)&ph[wid][l15 * 132 + ks * 32 + quad * 8];
#pragma unroll
        for (int dt = 0; dt < 4; ++dt) {
            int d = dt * 16 + l15;
#pragma unroll
            for (int ks = 0; ks < 4; ++ks) {
                half8 vv = *(const half8*)&vth[d * 144 + ((ks * 4 + quad + d) & 15) * 8];
                yacc[g][dt] = __builtin_amdgcn_mfma_f32_16x16x32_f16(pH[ks], vv, yacc[g][dt], 0, 0, 0);
            }
        }
    }

#pragma unroll
    for (int g = 0; g < 2; ++g) {
#pragma unroll
        for (int r = 0; r < 4; ++r) {
            float s1 = yacc[g][0][r] + yacc[g][1][r] + yacc[g][2][r] + yacc[g][3][r];
            float s2 = yacc[g][0][r] * yacc[g][0][r] + yacc[g][1][r] * yacc[g][1][r] +
                       yacc[g][2][r] * yacc[g][2][r] + yacc[g][3][r] * yacc[g][3][r];
#pragma unroll
            for (int o = 1; o <= 8; o <<= 1) {
                s1 += __shfl_xor(s1, o, 64);
                s2 += __shfl_xor(s2, o, 64);
            }
            float mu = s1 * (1.f / 64.f);
            float var = fmaxf(s2 * (1.f / 64.f) - mu * mu, 0.f);
            float rs = 1.f / sqrtf(var + 1e-5f);
            int nglob = n0 + wid * 32 + g * 16 + quad * 4 + r;
            size_t grow = (size_t)(b * 1024 + nglob);
#pragma unroll
            for (int dt = 0; dt < 4; ++dt) {
                int d = dt * 16 + l15;
                float yv = (yacc[g][dt][r] - mu) * rs;
                float gt = h2f(QKVGh[grow * 2048 + 1536 + h * 64 + d]);
                float sw = gt / (1.f + expf(-gt));
                Zh[grow * 512 + h * 64 + d] = f2h(yv * sw);
            }
        }
    }
}

// ---------- final reduce ----------
__global__ __launch_bounds__(256) void fc_final(const float* __restrict__ fcpart,
                                                const float* __restrict__ fcb,
                                                float* __restrict__ out)
{
    __shared__ float red[4];
    int b = blockIdx.x, t = threadIdx.x;
    float4 v = *(const float4*)&fcpart[(size_t)b * 1024 + t * 4];
    float s = v.x + v.y + v.z + v.w;
    int wid = t >> 6, lane = t & 63;
#pragma unroll
    for (int o = 32; o >= 1; o >>= 1) s += __shfl_xor(s, o, 64);
    if (lane == 0) red[wid] = s;
    __syncthreads();
    if (t == 0) {
        float l = red[0] + red[1] + red[2] + red[3] + fcb[0];
        out[b] = 1.f / (1.f + expf(-l));
    }
}

extern "C" void kernel_launch(void* const* d_in, const int* in_sizes, int n_in,
                              void* d_out, int out_size, void* d_ws, size_t ws_size,
                              hipStream_t stream)
{
    const int* ids = (const int*)d_in[0];
    const float* emb = (const float*)d_in[1];
    const float* pos = (const float*)d_in[2];
    const float* ln_g = (const float*)d_in[3];
    const float* ln_b = (const float*)d_in[4];
    const float* Wq = (const float*)d_in[5];
    const float* Wk = (const float*)d_in[6];
    const float* Wv = (const float*)d_in[7];
    const float* Wg = (const float*)d_in[8];
    const float* Wo = (const float*)d_in[9];
    const float* W1 = (const float*)d_in[10];
    const float* b1 = (const float*)d_in[11];
    const float* W2 = (const float*)d_in[12];
    const float* b2 = (const float*)d_in[13];
    const float* fcW = (const float*)d_in[14];
    const float* fcb = (const float*)d_in[15];
    float* out = (float*)d_out;

    char* ws = (char*)d_ws;
    u16* WT     = (u16*)(ws);                  //  3,670,016
    u16* x0h    = (u16*)(ws + 3670016);        //  8,388,608  LN(emb) f16 (A + residual)
    u16* Zh     = (u16*)(ws + 12058624);       //  8,388,608  retention out f16
    u16* QKVGh  = (u16*)(ws + 20447232);       // 33,554,432  [8192][2048] f16
    float* fcpart = (float*)(ws + 54001664);   // 32,768
    u16* Tst    = (u16*)(ws + 54034432);       //  4,194,304  per-chunk T [64bh][8][64][64]
    u16* X1h = QKVGh;                           // Wo out (residual for W2)
    u16* Th  = (u16*)((char*)QKVGh + 8388608);  // ln2 out
    u16* Hh  = (u16*)((char*)QKVGh + 16777216); // W1 out
    u16* X2h = Zh;                              // Zh dead after Wo-GEMM

    // only vocab iteration i=2 is live (x overwritten each pass)
    prep_kernel<<<2496, 256, 0, stream>>>(Wq, Wk, Wv, Wg, Wo, W1, W2, WT,
                                          ids, emb, pos, ln_g, ln_b, x0h);
    gemm_f16<<<dim3(16, 64), 256, 0, stream>>>(x0h, WT, QKVGh, 2048);
    chunk_t<<<512, 256, 0, stream>>>(QKVGh, Tst);
    retention_f16<<<512, 256, 0, stream>>>(QKVGh, Tst, Zh);
    gemm_f16_n64<<<dim3(8, 64), 256, 0, stream>>>(Zh, WT + 4 * 262144, X1h, x0h, nullptr, 1);
    ln_kernel<<<2048, 256, 0, stream>>>(X1h, ln_g, ln_b, Th, nullptr, nullptr);
    gemm_f16_n64<<<dim3(8, 64), 256, 0, stream>>>(Th, WT + 5 * 262144, Hh, nullptr, b1, 2);
    gemm_f16_n64<<<dim3(8, 64), 256, 0, stream>>>(Hh, WT + 6 * 262144, X2h, X1h, b2, 3);
    ln_kernel<<<2048, 256, 0, stream>>>(X2h, ln_g, ln_b, nullptr, fcW, fcpart);
    fc_final<<<8, 256, 0, stream>>>(fcpart, fcb, out);
}

// Round 18
// 226.885 us; speedup vs baseline: 1.1095x; 1.0167x over previous
//
#include <hip/hip_runtime.h>
#include <math.h>

typedef unsigned short u16;
typedef __attribute__((ext_vector_type(8))) _Float16 half8;
typedef __attribute__((ext_vector_type(4))) float f32x4;
typedef __attribute__((ext_vector_type(4))) unsigned short us4;

// Inputs f32, output f32 (proven r4-17). All inter-kernel activations f16.
// r18: LDS-bounce vectorized epilogues in both GEMMs (64 scalar u16 stores -> 8 b128).

static __device__ __forceinline__ u16 f2h(float f) {
    _Float16 h = (_Float16)f;
    return __builtin_bit_cast(u16, h);
}
static __device__ __forceinline__ float h2f(u16 u) {
    return (float)__builtin_bit_cast(_Float16, u);
}
static __device__ __forceinline__ void gl_lds16(const void* g, void* l) {
    __builtin_amdgcn_global_load_lds(
        (const __attribute__((address_space(1))) void*)g,
        (__attribute__((address_space(3))) void*)l, 16, 0, 0);
}

// ---------- prep: weight transpose (448 blocks) + embed-LN (2048 blocks) ----------
__global__ __launch_bounds__(256) void prep_kernel(
    const float* __restrict__ Wq, const float* __restrict__ Wk, const float* __restrict__ Wv,
    const float* __restrict__ Wg, const float* __restrict__ Wo, const float* __restrict__ W1,
    const float* __restrict__ W2, u16* __restrict__ WT,
    const int* __restrict__ ids, const float* __restrict__ emb, const float* __restrict__ pos,
    const float* __restrict__ gam, const float* __restrict__ bet, u16* __restrict__ x0h)
{
    __shared__ float tile[64][65];
    int bx = blockIdx.x, t = threadIdx.x;
    if (bx < 448) {
        const float* Ws[7] = {Wq, Wk, Wv, Wg, Wo, W1, W2};
        int w = bx >> 6, rem = bx & 63;
        int k0 = (rem >> 3) * 64, n0 = (rem & 7) * 64;
        const float* W = Ws[w];
        for (int c = t; c < 4096; c += 256) {
            int row = c >> 6, col = c & 63;
            tile[row][col] = W[(size_t)(k0 + row) * 512 + n0 + col];
        }
        __syncthreads();
        for (int c = t; c < 4096; c += 256) {
            int row = c >> 6, col = c & 63;
            WT[(size_t)w * 262144 + (size_t)(n0 + row) * 512 + k0 + col] = f2h(tile[col][row]);
        }
    } else {
        int wid = t >> 6, lane = t & 63;
        int row = (bx - 448) * 4 + wid;
        int col = lane * 8;
        int id = ids[2 * 8192 + row];
        const float* e = emb + (size_t)(2 * 1024 + id) * 512 + col;
        const float* p = pos + (size_t)(2 * 1024 + (row & 1023)) * 512 + col;
        float4 e0 = *(const float4*)e, e1 = *(const float4*)(e + 4);
        float4 p0 = *(const float4*)p, p1 = *(const float4*)(p + 4);
        float v[8] = {e0.x + p0.x, e0.y + p0.y, e0.z + p0.z, e0.w + p0.w,
                      e1.x + p1.x, e1.y + p1.y, e1.z + p1.z, e1.w + p1.w};
        float s1 = 0.f, s2 = 0.f;
#pragma unroll
        for (int j = 0; j < 8; ++j) { s1 += v[j]; s2 += v[j] * v[j]; }
#pragma unroll
        for (int o = 32; o >= 1; o >>= 1) {
            s1 += __shfl_xor(s1, o, 64);
            s2 += __shfl_xor(s2, o, 64);
        }
        float mu = s1 * (1.f / 512.f);
        float var = fmaxf(s2 * (1.f / 512.f) - mu * mu, 0.f);
        float rs = 1.f / sqrtf(var + 1e-5f);
        float4 g0 = *(const float4*)&gam[col], g1 = *(const float4*)&gam[col + 4];
        float4 b0 = *(const float4*)&bet[col], b1 = *(const float4*)&bet[col + 4];
        float gv[8] = {g0.x, g0.y, g0.z, g0.w, g1.x, g1.y, g1.z, g1.w};
        float bv[8] = {b0.x, b0.y, b0.z, b0.w, b1.x, b1.y, b1.z, b1.w};
        half8 hv;
#pragma unroll
        for (int j = 0; j < 8; ++j) hv[j] = (_Float16)((v[j] - mu) * rs * gv[j] + bv[j]);
        *(half8*)&x0h[(size_t)row * 512 + col] = hv;
    }
}

// ---------- LayerNorm, row-per-wave; optional fused FC partial ----------
__global__ __launch_bounds__(256) void ln_kernel(
    const u16* __restrict__ xin,
    const float* __restrict__ gam, const float* __restrict__ bet,
    u16* __restrict__ outh,
    const float* __restrict__ fcW, float* __restrict__ fcpart)
{
    int wid = threadIdx.x >> 6, lane = threadIdx.x & 63;
    int row = blockIdx.x * 4 + wid;
    int col = lane * 8;
    float v[8];
    half8 x = *(const half8*)&xin[(size_t)row * 512 + col];
#pragma unroll
    for (int j = 0; j < 8; ++j) v[j] = (float)x[j];
    float s1 = 0.f, s2 = 0.f;
#pragma unroll
    for (int j = 0; j < 8; ++j) { s1 += v[j]; s2 += v[j] * v[j]; }
#pragma unroll
    for (int o = 32; o >= 1; o >>= 1) {
        s1 += __shfl_xor(s1, o, 64);
        s2 += __shfl_xor(s2, o, 64);
    }
    float mu = s1 * (1.f / 512.f);
    float var = fmaxf(s2 * (1.f / 512.f) - mu * mu, 0.f);
    float rs = 1.f / sqrtf(var + 1e-5f);
    float4 g0 = *(const float4*)&gam[col], g1 = *(const float4*)&gam[col + 4];
    float4 b0 = *(const float4*)&bet[col], b1 = *(const float4*)&bet[col + 4];
    float gv[8] = {g0.x, g0.y, g0.z, g0.w, g1.x, g1.y, g1.z, g1.w};
    float bv[8] = {b0.x, b0.y, b0.z, b0.w, b1.x, b1.y, b1.z, b1.w};
    float y[8];
#pragma unroll
    for (int j = 0; j < 8; ++j) y[j] = (v[j] - mu) * rs * gv[j] + bv[j];
    if (outh) {
        half8 hv;
#pragma unroll
        for (int j = 0; j < 8; ++j) hv[j] = (_Float16)y[j];
        *(half8*)&outh[(size_t)row * 512 + col] = hv;
    }
    if (fcW) {
        int srow = row & 1023;
        const float* wp = &fcW[(size_t)srow * 512 + col];
        float4 w0 = *(const float4*)wp, w1 = *(const float4*)(wp + 4);
        float d = y[0] * w0.x + y[1] * w0.y + y[2] * w0.z + y[3] * w0.w +
                  y[4] * w1.x + y[5] * w1.y + y[6] * w1.z + y[7] * w1.w;
#pragma unroll
        for (int o = 32; o >= 1; o >>= 1) d += __shfl_xor(d, o, 64);
        if (lane == 0) fcpart[row] = d;
    }
}

// ---------- GEMM 128x128 tile (QKVG): gl_lds staging, BK=64, LDS-bounce epilogue ----------
__global__ __launch_bounds__(256) void gemm_f16(
    const u16* __restrict__ A2, const u16* __restrict__ Bg,
    u16* __restrict__ outh, int ostride)
{
    __shared__ u16 As[128 * 64];
    __shared__ u16 Bs[128 * 64];
    int t = threadIdx.x;
    int wid = t >> 6, lane = t & 63, quad = lane >> 4, l15 = lane & 15;
    int wm = wid >> 1, wn = wid & 1;
    int m0 = blockIdx.y * 128, n0 = blockIdx.x * 128;

    int srow = wid * 8 + (lane >> 3);
    int scol = (lane & 7) * 8;

    f32x4 acc[4][4];
#pragma unroll
    for (int a = 0; a < 4; ++a)
#pragma unroll
        for (int b = 0; b < 4; ++b) acc[a][b] = (f32x4){0.f, 0.f, 0.f, 0.f};

    for (int ki = 0; ki < 8; ++ki) {
        int k0 = ki * 64;
        __syncthreads();
#pragma unroll
        for (int i = 0; i < 4; ++i) {
            int r = i * 32 + srow;
            gl_lds16(&A2[(size_t)(m0 + r) * 512 + k0 + scol], &As[(i * 32 + wid * 8) * 64]);
            gl_lds16(&Bg[(size_t)(n0 + r) * 512 + k0 + scol], &Bs[(i * 32 + wid * 8) * 64]);
        }
        __syncthreads();
#pragma unroll
        for (int ks = 0; ks < 2; ++ks) {
            half8 af[4], bf[4];
#pragma unroll
            for (int tm = 0; tm < 4; ++tm)
                af[tm] = *(const half8*)&As[(wm * 64 + tm * 16 + l15) * 64 + ks * 32 + quad * 8];
#pragma unroll
            for (int tn = 0; tn < 4; ++tn)
                bf[tn] = *(const half8*)&Bs[(wn * 64 + tn * 16 + l15) * 64 + ks * 32 + quad * 8];
#pragma unroll
            for (int tm = 0; tm < 4; ++tm)
#pragma unroll
                for (int tn = 0; tn < 4; ++tn)
                    acc[tm][tn] = __builtin_amdgcn_mfma_f32_16x16x32_f16(af[tm], bf[tn], acc[tm][tn], 0, 0, 0);
        }
    }

    // LDS-bounce epilogue: two 64-row passes through As (16 KB = [64][128] u16)
#pragma unroll
    for (int hb = 0; hb < 2; ++hb) {
        __syncthreads();
        if (wm == hb) {
#pragma unroll
            for (int tm = 0; tm < 4; ++tm)
#pragma unroll
                for (int tn = 0; tn < 4; ++tn)
#pragma unroll
                    for (int r = 0; r < 4; ++r) {
                        int rl = tm * 16 + quad * 4 + r;
                        int cl = wn * 64 + tn * 16 + l15;
                        As[rl * 128 + cl] = f2h(acc[tm][tn][r]);
                    }
        }
        __syncthreads();
#pragma unroll
        for (int i = 0; i < 4; ++i) {
            int c = t + i * 256;
            int row = c >> 4, ch = c & 15;
            *(half8*)&outh[(size_t)(m0 + hb * 64 + row) * ostride + n0 + ch * 8] =
                *(const half8*)&As[row * 128 + ch * 8];
        }
    }
}

// ---------- GEMM 128x64 tile (N=512 layers): 512 blocks, LDS-bounce epilogue ----------
// mode 1: C+res16 ; 2: relu(C+bias) ; 3: C+bias+res16
__global__ __launch_bounds__(256) void gemm_f16_n64(
    const u16* __restrict__ A2, const u16* __restrict__ Bg,
    u16* __restrict__ outh,
    const u16* __restrict__ res, const float* __restrict__ bias, int mode)
{
    __shared__ u16 As[128 * 64];   // 16 KB (also the epilogue tile [128][64])
    __shared__ u16 Bs[64 * 64];    //  8 KB
    int t = threadIdx.x;
    int wid = t >> 6, lane = t & 63, quad = lane >> 4, l15 = lane & 15;
    int m0 = blockIdx.y * 128, n0 = blockIdx.x * 64;

    int srow = wid * 8 + (lane >> 3);
    int scol = (lane & 7) * 8;

    f32x4 acc[2][4];
#pragma unroll
    for (int a = 0; a < 2; ++a)
#pragma unroll
        for (int b = 0; b < 4; ++b) acc[a][b] = (f32x4){0.f, 0.f, 0.f, 0.f};

    for (int ki = 0; ki < 8; ++ki) {
        int k0 = ki * 64;
        __syncthreads();
#pragma unroll
        for (int i = 0; i < 4; ++i) {
            int r = i * 32 + srow;
            gl_lds16(&A2[(size_t)(m0 + r) * 512 + k0 + scol], &As[(i * 32 + wid * 8) * 64]);
        }
#pragma unroll
        for (int i = 0; i < 2; ++i) {
            int r = i * 32 + srow;
            gl_lds16(&Bg[(size_t)(n0 + r) * 512 + k0 + scol], &Bs[(i * 32 + wid * 8) * 64]);
        }
        __syncthreads();
#pragma unroll
        for (int ks = 0; ks < 2; ++ks) {
            half8 af[2], bf[4];
#pragma unroll
            for (int tm = 0; tm < 2; ++tm)
                af[tm] = *(const half8*)&As[(wid * 32 + tm * 16 + l15) * 64 + ks * 32 + quad * 8];
#pragma unroll
            for (int tn = 0; tn < 4; ++tn)
                bf[tn] = *(const half8*)&Bs[(tn * 16 + l15) * 64 + ks * 32 + quad * 8];
#pragma unroll
            for (int tm = 0; tm < 2; ++tm)
#pragma unroll
                for (int tn = 0; tn < 4; ++tn)
                    acc[tm][tn] = __builtin_amdgcn_mfma_f32_16x16x32_f16(af[tm], bf[tn], acc[tm][tn], 0, 0, 0);
        }
    }

    // epilogue: mode ops on f32, then LDS bounce -> vector stores
    __syncthreads();
#pragma unroll
    for (int tm = 0; tm < 2; ++tm) {
#pragma unroll
        for (int tn = 0; tn < 4; ++tn) {
            int n = n0 + tn * 16 + l15;
#pragma unroll
            for (int r = 0; r < 4; ++r) {
                int rl = wid * 32 + tm * 16 + quad * 4 + r;
                int m = m0 + rl;
                float v = acc[tm][tn][r];
                if (mode == 1) v += h2f(res[(size_t)m * 512 + n]);
                else if (mode == 2) v = fmaxf(v + bias[n], 0.f);
                else if (mode == 3) v += bias[n] + h2f(res[(size_t)m * 512 + n]);
                As[rl * 64 + tn * 16 + l15] = f2h(v);
            }
        }
    }
    __syncthreads();
#pragma unroll
    for (int i = 0; i < 4; ++i) {
        int c = t + i * 256;
        int row = c >> 3, ch = c & 7;
        *(half8*)&outh[(size_t)(m0 + row) * 512 + n0 + ch * 8] =
            *(const half8*)&As[row * 64 + ch * 8];
    }
}

// ---------- chunk T: per (b,h,c) — T_c[d'][d] = sum_m v[m][d']*k[m][d]*g^(127-mloc) ----------
__global__ __launch_bounds__(256) void chunk_t(
    const u16* __restrict__ QKVGh, u16* __restrict__ Tst)
{
    __shared__ u16 kth[64 * 144];
    __shared__ u16 vth[64 * 144];
    int t = threadIdx.x;
    int wid = t >> 6, lane = t & 63, quad = lane >> 4, l15 = lane & 15;
    int bh = blockIdx.x >> 3, c = blockIdx.x & 7;
    int b = bh >> 3, h = bh & 7;
    float gamma = 1.f - exp2f(-(float)(5 + h));
    float l2g = log2f(gamma);

    for (int cc = t; cc < 2048; cc += 256) {
        int d = cc & 63, mseg = cc >> 6;
        size_t gbase = (size_t)(b * 1024 + c * 128 + mseg * 4) * 2048 + h * 64 + d;
        us4 k4, v4;
#pragma unroll
        for (int i = 0; i < 4; ++i) {
            float kv = h2f(QKVGh[gbase + 512 + (size_t)i * 2048]);
            k4[i] = f2h(kv * exp2f((float)(127 - (mseg * 4 + i)) * l2g));
            v4[i] = QKVGh[gbase + 1024 + (size_t)i * 2048];
        }
        int base = d * 144 + (((mseg >> 1) + d) & 15) * 8 + (mseg & 1) * 4;
        *(us4*)&kth[base] = k4;
        *(us4*)&vth[base] = v4;
    }
    __syncthreads();
    f32x4 T[4];
#pragma unroll
    for (int dt = 0; dt < 4; ++dt) T[dt] = (f32x4){0.f, 0.f, 0.f, 0.f};
    int ra = wid * 16 + l15;
#pragma unroll
    for (int ks = 0; ks < 4; ++ks) {
        half8 av = *(const half8*)&vth[ra * 144 + ((ks * 4 + quad + ra) & 15) * 8];
#pragma unroll
        for (int dt = 0; dt < 4; ++dt) {
            int rb = dt * 16 + l15;
            half8 bk = *(const half8*)&kth[rb * 144 + ((ks * 4 + quad + rb) & 15) * 8];
            T[dt] = __builtin_amdgcn_mfma_f32_16x16x32_f16(av, bk, T[dt], 0, 0, 0);
        }
    }
#pragma unroll
    for (int dt = 0; dt < 4; ++dt)
#pragma unroll
        for (int r = 0; r < 4; ++r) {
            int i = wid * 16 + quad * 4 + r;
            int j = dt * 16 + l15;
            Tst[(((size_t)bh * 8 + c) * 64 + i) * 64 + j] = f2h(T[dt][r]);
        }
}

// ---------- retention: inline state prefix from Tst + single-chunk intra ----------
__global__ __launch_bounds__(256) void retention_f16(
    const u16* __restrict__ QKVGh, const u16* __restrict__ Tst, u16* __restrict__ Zh)
{
    __shared__ u16 kh[128 * 64];
    __shared__ u16 vth[64 * 144];
    __shared__ u16 ph[4][16 * 132];

    int t = threadIdx.x;
    int wid = t >> 6, lane = t & 63, quad = lane >> 4, l15 = lane & 15;
    int bh = blockIdx.x >> 3, qt = blockIdx.x & 7;
    int b = bh >> 3, h = bh & 7;
    int n0 = qt * 128;

    float gamma = 1.f - exp2f(-(float)(5 + h));
    float l2g = log2f(gamma);

    {
        int srow = wid * 8 + (lane >> 3);
        int scol = (lane & 7) * 8;
#pragma unroll
        for (int i = 0; i < 4; ++i) {
            int r = i * 32 + srow;
            gl_lds16(&QKVGh[(size_t)(b * 1024 + n0 + r) * 2048 + 512 + h * 64 + scol],
                     &kh[(i * 32 + wid * 8) * 64]);
        }
    }
    for (int c = t; c < 2048; c += 256) {
        int d = c & 63, mseg = c >> 6;
        size_t gbase = (size_t)(b * 1024 + n0 + mseg * 4) * 2048 + 1024 + h * 64 + d;
        us4 v4 = {QKVGh[gbase], QKVGh[gbase + 2048],
                  QKVGh[gbase + 4096], QKVGh[gbase + 6144]};
        int base = d * 144 + (((mseg >> 1) + d) & 15) * 8 + (mseg & 1) * 4;
        *(us4*)&vth[base] = v4;
    }

    half8 aH[2][2], aHs[2][2];
#pragma unroll
    for (int g = 0; g < 2; ++g) {
        int rowloc = wid * 32 + g * 16 + l15;
        int qrow = b * 1024 + n0 + rowloc;
        const u16* qp = QKVGh + (size_t)qrow * 2048 + h * 64;
        float qs = exp2f((float)(rowloc + 1) * l2g - 3.f);
#pragma unroll
        for (int ks = 0; ks < 2; ++ks) {
            aH[g][ks] = *(const half8*)&qp[ks * 32 + quad * 8];
#pragma unroll
            for (int j = 0; j < 8; ++j)
                aHs[g][ks][j] = (_Float16)((float)aH[g][ks][j] * qs);
        }
    }

    half8 sf[2][4];
    if (qt > 0) {
        float sa[2][4][8];
#pragma unroll
        for (int ks = 0; ks < 2; ++ks)
#pragma unroll
            for (int dt = 0; dt < 4; ++dt)
#pragma unroll
                for (int j = 0; j < 8; ++j) sa[ks][dt][j] = 0.f;
        for (int c = 0; c < qt; ++c) {
            float sc = exp2f((float)(128 * (qt - 1 - c)) * l2g);
            const u16* tp = &Tst[((size_t)bh * 8 + c) * 4096];
#pragma unroll
            for (int ks = 0; ks < 2; ++ks)
#pragma unroll
                for (int dt = 0; dt < 4; ++dt) {
                    half8 tv = *(const half8*)&tp[(dt * 16 + l15) * 64 + ks * 32 + quad * 8];
#pragma unroll
                    for (int j = 0; j < 8; ++j) sa[ks][dt][j] += sc * (float)tv[j];
                }
        }
#pragma unroll
        for (int ks = 0; ks < 2; ++ks)
#pragma unroll
            for (int dt = 0; dt < 4; ++dt)
#pragma unroll
                for (int j = 0; j < 8; ++j) sf[ks][dt][j] = (_Float16)sa[ks][dt][j];
    }
    __syncthreads();

    f32x4 yacc[2][4];
#pragma unroll
    for (int g = 0; g < 2; ++g)
#pragma unroll
        for (int dt = 0; dt < 4; ++dt) yacc[g][dt] = (f32x4){0.f, 0.f, 0.f, 0.f};

    if (qt > 0) {
#pragma unroll
        for (int ks = 0; ks < 2; ++ks)
#pragma unroll
            for (int g = 0; g < 2; ++g)
#pragma unroll
                for (int dt = 0; dt < 4; ++dt)
                    yacc[g][dt] = __builtin_amdgcn_mfma_f32_16x16x32_f16(aHs[g][ks], sf[ks][dt], yacc[g][dt], 0, 0, 0);
    }

#pragma unroll
    for (int g = 0; g < 2; ++g) {
        f32x4 sacc[8];
#pragma unroll
        for (int tn = 0; tn < 8; ++tn) sacc[tn] = (f32x4){0.f, 0.f, 0.f, 0.f};
#pragma unroll
        for (int tn = 0; tn < 8; ++tn)
#pragma unroll
            for (int ks = 0; ks < 2; ++ks) {
                half8 bH = *(const half8*)&kh[(tn * 16 + l15) * 64 + ks * 32 + quad * 8];
                sacc[tn] = __builtin_amdgcn_mfma_f32_16x16x32_f16(aH[g][ks], bH, sacc[tn], 0, 0, 0);
            }
#pragma unroll
        for (int tn = 0; tn < 8; ++tn) {
            int mloc = tn * 16 + l15;
#pragma unroll
            for (int r = 0; r < 4; ++r) {
                int nloc = wid * 32 + g * 16 + quad * 4 + r;
                int diff = nloc - mloc;
                float p = (diff >= 0) ? sacc[tn][r] * exp2f((float)diff * l2g - 3.0f) : 0.f;
                ph[wid][(quad * 4 + r) * 132 + tn * 16 + l15] = f2h(p);
            }
        }
        half8 pH[4];
#pragma unroll
        for (int ks = 0; ks < 4; ++ks)
            pH[ks] = *(const half8*)&ph[wid][l15 * 132 + ks * 32 + quad * 8];
#pragma unroll
        for (int dt = 0; dt < 4; ++dt) {
            int d = dt * 16 + l15;
#pragma unroll
            for (int ks = 0; ks < 4; ++ks) {
                half8 vv = *(const half8*)&vth[d * 144 + ((ks * 4 + quad + d) & 15) * 8];
                yacc[g][dt] = __builtin_amdgcn_mfma_f32_16x16x32_f16(pH[ks], vv, yacc[g][dt], 0, 0, 0);
            }
        }
    }

#pragma unroll
    for (int g = 0; g < 2; ++g) {
#pragma unroll
        for (int r = 0; r < 4; ++r) {
            float s1 = yacc[g][0][r] + yacc[g][1][r] + yacc[g][2][r] + yacc[g][3][r];
            float s2 = yacc[g][0][r] * yacc[g][0][r] + yacc[g][1][r] * yacc[g][1][r] +
                       yacc[g][2][r] * yacc[g][2][r] + yacc[g][3][r] * yacc[g][3][r];
#pragma unroll
            for (int o = 1; o <= 8; o <<= 1) {
                s1 += __shfl_xor(s1, o, 64);
                s2 += __shfl_xor(s2, o, 64);
            }
            float mu = s1 * (1.f / 64.f);
            float var = fmaxf(s2 * (1.f / 64.f) - mu * mu, 0.f);
            float rs = 1.f / sqrtf(var + 1e-5f);
            int nglob = n0 + wid * 32 + g * 16 + quad * 4 + r;
            size_t grow = (size_t)(b * 1024 + nglob);
#pragma unroll
            for (int dt = 0; dt < 4; ++dt) {
                int d = dt * 16 + l15;
                float yv = (yacc[g][dt][r] - mu) * rs;
                float gt = h2f(QKVGh[grow * 2048 + 1536 + h * 64 + d]);
                float sw = gt / (1.f + expf(-gt));
                Zh[grow * 512 + h * 64 + d] = f2h(yv * sw);
            }
        }
    }
}

// ---------- final reduce ----------
__global__ __launch_bounds__(256) void fc_final(const float* __restrict__ fcpart,
                                                const float* __restrict__ fcb,
                                                float* __restrict__ out)
{
    __shared__ float red[4];
    int b = blockIdx.x, t = threadIdx.x;
    float4 v = *(const float4*)&fcpart[(size_t)b * 1024 + t * 4];
    float s = v.x + v.y + v.z + v.w;
    int wid = t >> 6, lane = t & 63;
#pragma unroll
    for (int o = 32; o >= 1; o >>= 1) s += __shfl_xor(s, o, 64);
    if (lane == 0) red[wid] = s;
    __syncthreads();
    if (t == 0) {
        float l = red[0] + red[1] + red[2] + red[3] + fcb[0];
        out[b] = 1.f / (1.f + expf(-l));
    }
}

extern "C" void kernel_launch(void* const* d_in, const int* in_sizes, int n_in,
                              void* d_out, int out_size, void* d_ws, size_t ws_size,
                              hipStream_t stream)
{
    const int* ids = (const int*)d_in[0];
    const float* emb = (const float*)d_in[1];
    const float* pos = (const float*)d_in[2];
    const float* ln_g = (const float*)d_in[3];
    const float* ln_b = (const float*)d_in[4];
    const float* Wq = (const float*)d_in[5];
    const float* Wk = (const float*)d_in[6];
    const float* Wv = (const float*)d_in[7];
    const float* Wg = (const float*)d_in[8];
    const float* Wo = (const float*)d_in[9];
    const float* W1 = (const float*)d_in[10];
    const float* b1 = (const float*)d_in[11];
    const float* W2 = (const float*)d_in[12];
    const float* b2 = (const float*)d_in[13];
    const float* fcW = (const float*)d_in[14];
    const float* fcb = (const float*)d_in[15];
    float* out = (float*)d_out;

    char* ws = (char*)d_ws;
    u16* WT     = (u16*)(ws);                  //  3,670,016
    u16* x0h    = (u16*)(ws + 3670016);        //  8,388,608  LN(emb) f16 (A + residual)
    u16* Zh     = (u16*)(ws + 12058624);       //  8,388,608  retention out f16
    u16* QKVGh  = (u16*)(ws + 20447232);       // 33,554,432  [8192][2048] f16
    float* fcpart = (float*)(ws + 54001664);   // 32,768
    u16* Tst    = (u16*)(ws + 54034432);       //  4,194,304  per-chunk T [64bh][8][64][64]
    u16* X1h = QKVGh;                           // Wo out (residual for W2)
    u16* Th  = (u16*)((char*)QKVGh + 8388608);  // ln2 out
    u16* Hh  = (u16*)((char*)QKVGh + 16777216); // W1 out
    u16* X2h = Zh;                              // Zh dead after Wo-GEMM

    // only vocab iteration i=2 is live (x overwritten each pass)
    prep_kernel<<<2496, 256, 0, stream>>>(Wq, Wk, Wv, Wg, Wo, W1, W2, WT,
                                          ids, emb, pos, ln_g, ln_b, x0h);
    gemm_f16<<<dim3(16, 64), 256, 0, stream>>>(x0h, WT, QKVGh, 2048);
    chunk_t<<<512, 256, 0, stream>>>(QKVGh, Tst);
    retention_f16<<<512, 256, 0, stream>>>(QKVGh, Tst, Zh);
    gemm_f16_n64<<<dim3(8, 64), 256, 0, stream>>>(Zh, WT + 4 * 262144, X1h, x0h, nullptr, 1);
    ln_kernel<<<2048, 256, 0, stream>>>(X1h, ln_g, ln_b, Th, nullptr, nullptr);
    gemm_f16_n64<<<dim3(8, 64), 256, 0, stream>>>(Th, WT + 5 * 262144, Hh, nullptr, b1, 2);
    gemm_f16_n64<<<dim3(8, 64), 256, 0, stream>>>(Hh, WT + 6 * 262144, X2h, X1h, b2, 3);
    ln_kernel<<<2048, 256, 0, stream>>>(X2h, ln_g, ln_b, nullptr, fcW, fcpart);
    fc_final<<<8, 256, 0, stream>>>(fcpart, fcb, out);
}